// Round 2
// baseline (309.339 us; speedup 1.0000x reference)
//
#include <hip/hip_runtime.h>
#include <math.h>

#define D100 100
#define NE 50000
#define BATCH 16
#define EPS_F 1e-5f
#define NB_MAX 360

// ---------------------------------------------------------------------------
// K1 fallback (monolithic): Wm[t][b][e][f] = sum_k R2[r_idx[b]][k] * W_t[k][e][f]
__global__ void k1_wm(const float* __restrict__ W_re, const float* __restrict__ W_im,
                      const float* __restrict__ R2, const int* __restrict__ r_idx,
                      float* __restrict__ Wm) {
  const int t = blockIdx.y;
  const float* W = t ? W_im : W_re;
  int ef = blockIdx.x * 256 + threadIdx.x;
  if (ef >= 10000) return;
  int ridx[16];
#pragma unroll
  for (int b = 0; b < 16; b++) ridx[b] = r_idx[b];
  float acc[16];
#pragma unroll
  for (int b = 0; b < 16; b++) acc[b] = 0.f;
  for (int k = 0; k < 100; k++) {
    float w = W[k * 10000 + ef];
#pragma unroll
    for (int b = 0; b < 16; b++) acc[b] = fmaf(R2[ridx[b] * 100 + k], w, acc[b]);
  }
  float* o = Wm + t * 160000 + ef;
#pragma unroll
  for (int b = 0; b < 16; b++) o[b * 10000] = acc[b];
}

// ---------------------------------------------------------------------------
// K1a: split-K partials. Wm_p[kc][t][b][ef] = sum_{k in chunk kc} R2[..][k]*W[k][ef]
// grid (10, 4, 2), block 256; each thread owns 4 consecutive ef (one float4).
__global__ void k1a_wm(const float* __restrict__ W_re, const float* __restrict__ W_im,
                       const float* __restrict__ R2, const int* __restrict__ r_idx,
                       float* __restrict__ Wm_p) {
  const int t = blockIdx.z, kc = blockIdx.y;
  const float* W = t ? W_im : W_re;
  const float4* W4 = (const float4*)W;
  __shared__ float r2s[16][28];
  const int tid = threadIdx.x;
  for (int i = tid; i < 400; i += 256) {
    int b = i / 25, kk = i - b * 25;
    r2s[b][kk] = R2[r_idx[b] * 100 + kc * 25 + kk];
  }
  __syncthreads();
  int ef4 = blockIdx.x * 256 + tid;
  if (ef4 < 2500) {
    float4 acc[16];
#pragma unroll
    for (int b = 0; b < 16; b++) acc[b] = make_float4(0.f, 0.f, 0.f, 0.f);
#pragma unroll 5
    for (int kk = 0; kk < 25; kk++) {
      float4 w = W4[(kc * 25 + kk) * 2500 + ef4];
#pragma unroll
      for (int b = 0; b < 16; b++) {
        float r = r2s[b][kk];
        acc[b].x = fmaf(r, w.x, acc[b].x);
        acc[b].y = fmaf(r, w.y, acc[b].y);
        acc[b].z = fmaf(r, w.z, acc[b].z);
        acc[b].w = fmaf(r, w.w, acc[b].w);
      }
    }
    float4* o = (float4*)(Wm_p + (long)kc * 320000 + t * 160000);
#pragma unroll
    for (int b = 0; b < 16; b++) o[b * 2500 + ef4] = acc[b];
  }
}

// K1b: Wm = sum over 4 kc partials.  grid (313), block 256 (float4 elements)
__global__ void k1b_reduce(const float* __restrict__ Wm_p, float* __restrict__ Wm) {
  int i4 = blockIdx.x * 256 + threadIdx.x;
  if (i4 >= 80000) return;
  const float4* P4 = (const float4*)Wm_p;
  float4 a = P4[i4], b = P4[80000 + i4], c = P4[160000 + i4], d = P4[240000 + i4];
  float4 o;
  o.x = a.x + b.x + c.x + d.x;
  o.y = a.y + b.y + c.y + d.y;
  o.z = a.z + b.z + c.z + d.z;
  o.w = a.w + b.w + c.w + d.w;
  ((float4*)Wm)[i4] = o;
}

// ---------------------------------------------------------------------------
// K2: block-partial Gram G = E^T E, double-buffered LDS, 8x8 register tiles
// grid (NB, 2), block 256
__global__ __launch_bounds__(256, 4) void k2_gram(const float* __restrict__ E_a,
                                                  const float* __restrict__ E_b,
                                                  float* __restrict__ Gp,
                                                  float* __restrict__ CSp,
                                                  int NB, int RPB) {
  const int t = blockIdx.y;
  const float* E = t ? E_b : E_a;
  const float4* E4 = (const float4*)E;
  __shared__ float sm[2][32][128];
  const int tid = threadIdx.x;
  const int bx = blockIdx.x;
  int r0 = bx * RPB;
  int rend = min(r0 + RPB, NE);

  // zero pad columns 100..127 of both buffers once
  for (int i = tid; i < 2 * 32 * 28; i += 256) {
    int buf = i / (32 * 28);
    int rem = i - buf * (32 * 28);
    int r = rem / 28;
    sm[buf][r][100 + (rem - r * 28)] = 0.f;
  }

  float4 st[4];
#define LOAD_CHUNK(base)                                     \
  {                                                          \
    _Pragma("unroll")                                        \
    for (int s = 0; s < 4; s++) {                            \
      int i = s * 256 + tid;                                 \
      float4 v = make_float4(0.f, 0.f, 0.f, 0.f);            \
      if (i < 800) {                                         \
        int r = i / 25, c4 = i - r * 25;                     \
        int row = (base) + r;                                \
        if (row < rend) v = E4[row * 25 + c4];               \
      }                                                      \
      st[s] = v;                                             \
    }                                                        \
  }
#define WRITE_CHUNK(buf)                                     \
  {                                                          \
    _Pragma("unroll")                                        \
    for (int s = 0; s < 4; s++) {                            \
      int i = s * 256 + tid;                                 \
      if (i < 800) {                                         \
        int r = i / 25, c4 = i - r * 25;                     \
        *(float4*)&sm[buf][r][c4 * 4] = st[s];               \
      }                                                      \
    }                                                        \
  }

  float acc[8][8];
#pragma unroll
  for (int i = 0; i < 8; i++)
#pragma unroll
    for (int j = 0; j < 8; j++) acc[i][j] = 0.f;
  float cs = 0.f;
  const int ty = tid >> 4, tx = tid & 15;

  LOAD_CHUNK(r0);
  WRITE_CHUNK(0);
  __syncthreads();
  int nch = (rend - r0 + 31) / 32;
  for (int c = 0; c < nch; c++) {
    int buf = c & 1;
    if (c + 1 < nch) LOAD_CHUNK(r0 + (c + 1) * 32);  // global loads in flight
#pragma unroll 2
    for (int r = 0; r < 32; r++) {
      float4 a0 = *(const float4*)&sm[buf][r][ty * 8];
      float4 a1 = *(const float4*)&sm[buf][r][ty * 8 + 4];
      float4 b0 = *(const float4*)&sm[buf][r][tx * 8];
      float4 b1 = *(const float4*)&sm[buf][r][tx * 8 + 4];
      float av[8] = {a0.x, a0.y, a0.z, a0.w, a1.x, a1.y, a1.z, a1.w};
      float bv[8] = {b0.x, b0.y, b0.z, b0.w, b1.x, b1.y, b1.z, b1.w};
#pragma unroll
      for (int i = 0; i < 8; i++)
#pragma unroll
        for (int j = 0; j < 8; j++) acc[i][j] = fmaf(av[i], bv[j], acc[i][j]);
    }
    if (tid < 100) {
#pragma unroll 4
      for (int r = 0; r < 32; r++) cs += sm[buf][r][tid];
    }
    __syncthreads();  // everyone done reading buf
    if (c + 1 < nch) {
      WRITE_CHUNK(buf ^ 1);
      __syncthreads();
    }
  }

  float* gp = Gp + (t * NB + bx) * 10000;
#pragma unroll
  for (int i = 0; i < 8; i++) {
    int e = ty * 8 + i;
    if (e < 100) {
#pragma unroll
      for (int j = 0; j < 8; j++) {
        int ep = tx * 8 + j;
        if (ep < 100) gp[e * 100 + ep] = acc[i][j];
      }
    }
  }
  if (tid < 100) CSp[(t * NB + bx) * 100 + tid] = cs;
}

// ---------------------------------------------------------------------------
// K3: reduce Gram partials and colsum partials.  grid (80), block 256
__global__ void k3_reduce(const float* __restrict__ Gp, const float* __restrict__ CSp,
                          float* __restrict__ G, float* __restrict__ CS, int NB) {
  int bid = blockIdx.x;
  int t = bid / 40, chunk = bid - t * 40;
  int idx = chunk * 256 + threadIdx.x;
  if (idx < 10000) {
    float s = 0.f;
    const float* p = Gp + (long)t * NB * 10000 + idx;
    for (int nb = 0; nb < NB; nb++) s += p[(long)nb * 10000];
    G[t * 10000 + idx] = s;
  }
  if (chunk == 0 && threadIdx.x < 100) {
    float s = 0.f;
    const float* p = CSp + (long)t * NB * 100 + threadIdx.x;
    for (int nb = 0; nb < NB; nb++) s += p[nb * 100];
    CS[t * 100 + threadIdx.x] = s;
  }
}

// ---------------------------------------------------------------------------
// K4: gather h, BN2 over batch, per-batch matvec with Wm -> traw.  grid (16), block 256
__global__ void k4_core1(const float* __restrict__ E_a, const float* __restrict__ E_b,
                         const int* __restrict__ h_idx, const float* __restrict__ Wm,
                         const float* __restrict__ g0r, const float* __restrict__ b0r,
                         const float* __restrict__ g0i, const float* __restrict__ b0i,
                         float* __restrict__ traw) {
  __shared__ float ha[1600], hb[1600], xa[100], xb[100];
  int tid = threadIdx.x, bo = blockIdx.x;
  for (int idx = tid; idx < 1600; idx += 256) {
    int bb = idx / 100, e = idx - bb * 100;
    int h = h_idx[bb];
    ha[idx] = E_a[h * 100 + e];
    hb[idx] = E_b[h * 100 + e];
  }
  __syncthreads();
  if (tid < 100) {
    float m = 0.f, s = 0.f;
#pragma unroll
    for (int b = 0; b < 16; b++) { float v = ha[b * 100 + tid]; m += v; s += v * v; }
    m *= (1.f / 16.f);
    float var = s * (1.f / 16.f) - m * m;
    xa[tid] = (ha[bo * 100 + tid] - m) * rsqrtf(var + EPS_F) * g0r[tid] + b0r[tid];
    m = 0.f; s = 0.f;
#pragma unroll
    for (int b = 0; b < 16; b++) { float v = hb[b * 100 + tid]; m += v; s += v * v; }
    m *= (1.f / 16.f);
    var = s * (1.f / 16.f) - m * m;
    xb[tid] = (hb[bo * 100 + tid] - m) * rsqrtf(var + EPS_F) * g0i[tid] + b0i[tid];
  }
  __syncthreads();
  if (tid < 100) {
    float sa = 0.f, sb = 0.f;
    const float* wa = Wm + bo * 10000 + tid;
    const float* wb = Wm + 160000 + bo * 10000 + tid;
    for (int e = 0; e < 100; e++) {
      sa = fmaf(xa[e], wa[e * 100], sa);
      sb = fmaf(xb[e], wb[e * 100], sb);
    }
    traw[bo * 100 + tid] = sa;
    traw[1600 + bo * 100 + tid] = sb;
  }
}

// ---------------------------------------------------------------------------
// K5: BN2 of traw + Mobius -> t0,t1.  grid(1), block 256
__global__ void k5_core2(const float* __restrict__ traw,
                         const float* __restrict__ R_re, const float* __restrict__ R_im,
                         const int* __restrict__ r_idx,
                         const float* __restrict__ g1r, const float* __restrict__ b1r,
                         const float* __restrict__ g1i, const float* __restrict__ b1i,
                         float* __restrict__ t01) {
  __shared__ float ta[1600], tb[1600], sca[100], sha[100], scb[100], shb[100];
  int tid = threadIdx.x;
  for (int i = tid; i < 1600; i += 256) { ta[i] = traw[i]; tb[i] = traw[1600 + i]; }
  __syncthreads();
  if (tid < 100) {
    float m = 0.f, s = 0.f;
#pragma unroll
    for (int b = 0; b < 16; b++) { float v = ta[b * 100 + tid]; m += v; s += v * v; }
    m *= (1.f / 16.f);
    float var = s * (1.f / 16.f) - m * m;
    float sc = rsqrtf(var + EPS_F) * g1r[tid];
    sca[tid] = sc; sha[tid] = b1r[tid] - m * sc;
    m = 0.f; s = 0.f;
#pragma unroll
    for (int b = 0; b < 16; b++) { float v = tb[b * 100 + tid]; m += v; s += v * v; }
    m *= (1.f / 16.f);
    var = s * (1.f / 16.f) - m * m;
    sc = rsqrtf(var + EPS_F) * g1i[tid];
    scb[tid] = sc; shb[tid] = b1i[tid] - m * sc;
  }
  __syncthreads();
  for (int idx = tid; idx < 1600; idx += 256) {
    int b = idx / 100, f = idx - b * 100;
    float va = ta[idx] * sca[f] + sha[f];
    float vb = tb[idx] * scb[f] + shb[f];
    int base = r_idx[b] * 400 + f;
    float ra0 = R_re[base],       ra1 = R_im[base];
    float rb0 = R_re[base + 100], rb1 = R_im[base + 100];
    float rc0 = R_re[base + 200], rc1 = R_im[base + 200];
    float rd0 = R_re[base + 300], rd1 = R_im[base + 300];
    float top0 = va * ra0 - vb * ra1 + rb0;
    float top1 = va * ra1 + vb * ra0 + rb1;
    float bot0 = va * rc0 - vb * rc1 + rd0;
    float bot1 = va * rc1 + vb * rc0 + rd1;
    float den = bot0 * bot0 + bot1 * bot1;
    t01[idx]        = (top0 * bot0 + top1 * bot1) / den;
    t01[1600 + idx] = (top1 * bot0 - top0 * bot1) / den;
  }
}

// ---------------------------------------------------------------------------
// K6: P[t][b][ep][f] = (sum_e Wm[t][b][e][f] * G[t][e][ep]) * Wm[t][b][ep][f]
// grid (40, 16, 2), block 256
__global__ void k6_v(const float* __restrict__ Wm, const float* __restrict__ G,
                     float* __restrict__ P) {
  int t = blockIdx.z, b = blockIdx.y;
  int ef = blockIdx.x * 256 + threadIdx.x;
  if (ef >= 10000) return;
  int ep = ef / 100, f = ef - ep * 100;
  const float* Wmt = Wm + t * 160000 + b * 10000;
  const float* Gt = G + t * 10000 + ep;
  float a = 0.f;
  for (int e = 0; e < 100; e++) a = fmaf(Wmt[e * 100 + f], Gt[e * 100], a);
  P[t * 160000 + b * 10000 + ef] = a * Wmt[ep * 100 + f];
}

// ---------------------------------------------------------------------------
// K7: per-f BN3 stats -> alpha,beta.  grid (100, 2), block 256
__global__ void k7_stats(const float* __restrict__ P, const float* __restrict__ Wm,
                         const float* __restrict__ CS,
                         const float* __restrict__ gEa, const float* __restrict__ bEa,
                         const float* __restrict__ gEb, const float* __restrict__ bEb,
                         float* __restrict__ alpha, float* __restrict__ beta) {
  int f = blockIdx.x, t = blockIdx.y, tid = threadIdx.x;
  __shared__ float r1[256], r2[256];
  float s1 = 0.f, s2 = 0.f;
  const float* Pp = P + t * 160000 + f;
  const float* Wp = Wm + t * 160000 + f;
  const float* csp = CS + t * 100;
  for (int p = tid; p < 1600; p += 256) {
    s1 += Pp[p * 100];
    int e = p - (p / 100) * 100;
    s2 += Wp[p * 100] * csp[e];
  }
  r1[tid] = s1; r2[tid] = s2;
  __syncthreads();
  for (int o = 128; o > 0; o >>= 1) {
    if (tid < o) { r1[tid] += r1[tid + o]; r2[tid] += r2[tid + o]; }
    __syncthreads();
  }
  if (tid == 0) {
    float mean = r2[0] * (1.f / 800000.f);
    float var = r1[0] * (1.f / 800000.f) - mean * mean;
    float g = t ? gEb[f] : gEa[f];
    float bb = t ? bEb[f] : bEa[f];
    float al = rsqrtf(var + EPS_F) * g;
    alpha[t * 100 + f] = al;
    beta[t * 100 + f] = bb - mean * al;
  }
}

// ---------------------------------------------------------------------------
// K8: u, c.  grid (16), block 128
__global__ void k8_u(const float* __restrict__ t01, const float* __restrict__ alpha,
                     const float* __restrict__ beta, const float* __restrict__ Wm,
                     float* __restrict__ u, float* __restrict__ c) {
  int b = blockIdx.x, tid = threadIdx.x;
  __shared__ float w0[100], w1[100], pc[128];
  float p = 0.f;
  if (tid < 100) {
    float t0 = t01[b * 100 + tid], t1 = t01[1600 + b * 100 + tid];
    w0[tid] = t0 * alpha[tid];
    w1[tid] = t1 * alpha[100 + tid];
    p = t0 * beta[tid] + t1 * beta[100 + tid];
  }
  pc[tid] = (tid < 100) ? p : 0.f;
  __syncthreads();
  for (int o = 64; o > 0; o >>= 1) {
    if (tid < o) pc[tid] += pc[tid + o];
    __syncthreads();
  }
  if (tid == 0) c[b] = pc[0];
  if (tid < 100) {
    float sa = 0.f, sb = 0.f;
    const float* wa = Wm + b * 10000 + tid * 100;
    const float* wb = Wm + 160000 + b * 10000 + tid * 100;
    for (int f = 0; f < 100; f++) {
      sa = fmaf(w0[f], wa[f], sa);
      sb = fmaf(w1[f], wb[f], sb);
    }
    u[tid * 16 + b] = sa;
    u[(100 + tid) * 16 + b] = sb;
  }
}

// ---------------------------------------------------------------------------
// K9: score = sigmoid(c + u_a·E_a + u_b·E_b).  grid (196), block 256
__device__ __forceinline__ float f4get(const float4& v, int j) {
  switch (j) { case 0: return v.x; case 1: return v.y; case 2: return v.z; default: return v.w; }
}

__global__ __launch_bounds__(256) void k9_score(const float* __restrict__ E_a,
                                                const float* __restrict__ E_b,
                                                const float* __restrict__ u,
                                                const float* __restrict__ c,
                                                float* __restrict__ out) {
  int n = blockIdx.x * 256 + threadIdx.x;
  if (n >= NE) return;
  const float4* Ea4 = (const float4*)E_a;
  const float4* Eb4 = (const float4*)E_b;
  float acc[16];
#pragma unroll
  for (int b = 0; b < 16; b++) acc[b] = 0.f;
  for (int e4 = 0; e4 < 25; e4++) {
    float4 va = Ea4[n * 25 + e4];
    float4 vb = Eb4[n * 25 + e4];
    const float* ua = u + e4 * 64;
    const float* ub = u + 1600 + e4 * 64;
#pragma unroll
    for (int j = 0; j < 4; j++) {
      float fa = f4get(va, j);
      float fb = f4get(vb, j);
#pragma unroll
      for (int b = 0; b < 16; b++) {
        acc[b] = fmaf(ua[j * 16 + b], fa, acc[b]);
        acc[b] = fmaf(ub[j * 16 + b], fb, acc[b]);
      }
    }
  }
#pragma unroll
  for (int b = 0; b < 16; b++) {
    float x = acc[b] + c[b];
    out[b * NE + n] = 1.f / (1.f + expf(-x));
  }
}

// ---------------------------------------------------------------------------
extern "C" void kernel_launch(void* const* d_in, const int* in_sizes, int n_in,
                              void* d_out, int out_size, void* d_ws, size_t ws_size,
                              hipStream_t stream) {
  const int* h_idx = (const int*)d_in[0];
  const int* r_idx = (const int*)d_in[1];
  const float* E_a = (const float*)d_in[2];
  const float* E_b = (const float*)d_in[3];
  const float* R_re = (const float*)d_in[4];
  const float* R_im = (const float*)d_in[5];
  const float* R2 = (const float*)d_in[6];
  const float* W_re = (const float*)d_in[7];
  const float* W_im = (const float*)d_in[8];
  const float* g0r = (const float*)d_in[9];
  const float* b0r = (const float*)d_in[10];
  const float* g1r = (const float*)d_in[11];
  const float* b1r = (const float*)d_in[12];
  const float* g0i = (const float*)d_in[13];
  const float* b0i = (const float*)d_in[14];
  const float* g1i = (const float*)d_in[15];
  const float* b1i = (const float*)d_in[16];
  const float* gEa = (const float*)d_in[17];
  const float* bEa = (const float*)d_in[18];
  const float* gEb = (const float*)d_in[19];
  const float* bEb = (const float*)d_in[20];
  float* out = (float*)d_out;
  float* ws = (float*)d_ws;

  // fixed regions (350,216 floats)
  float* Wm = ws;                  // [2][16][10000]   320000
  float* G = Wm + 320000;          // [2][10000]        20000
  float* CS = G + 20000;           // [2][100]            200
  float* traw = CS + 200;          // [2][16][100]       3200
  float* t01 = traw + 3200;        // [2][16][100]       3200
  float* alpha = t01 + 3200;       //                     200
  float* beta = alpha + 200;       //                     200
  float* u = beta + 200;           // [2][100][16]       3200
  float* c = u + 3200;             //                      16
  const long fixed = 350216;

  // union region: Wm_p (k1a->k1b), Gp+CSp (k2->k3), P (k6->k7) have disjoint
  // lifetimes on the serial stream and share this space.
  float* un = ws + fixed;
  long avail = (long)(ws_size / 4);
  long unionFloats = avail - fixed - 64;

  const long per_nb = 2 * 10000 + 2 * 100;
  int NB = NB_MAX;
  long room = unionFloats / per_nb;
  if (room < NB) NB = (int)room;
  if (NB < 1) NB = 1;
  int RPB = (NE + NB - 1) / NB;

  float* Gp = un;                       // [2][NB][10000]
  float* CSp = Gp + (long)NB * 20000;   // [2][NB][100]
  float* P = un;                        // [2][16][10000]
  float* Wm_p = un;                     // [4][2][16][10000] = 1,280,000
  int splitK1 = (unionFloats >= 1280000);

  if (splitK1) {
    hipLaunchKernelGGL(k1a_wm, dim3(10, 4, 2), dim3(256), 0, stream, W_re, W_im, R2, r_idx, Wm_p);
    hipLaunchKernelGGL(k1b_reduce, dim3(313), dim3(256), 0, stream, Wm_p, Wm);
  } else {
    hipLaunchKernelGGL(k1_wm, dim3(40, 2), dim3(256), 0, stream, W_re, W_im, R2, r_idx, Wm);
  }
  hipLaunchKernelGGL(k2_gram, dim3(NB, 2), dim3(256), 0, stream, E_a, E_b, Gp, CSp, NB, RPB);
  hipLaunchKernelGGL(k3_reduce, dim3(80), dim3(256), 0, stream, Gp, CSp, G, CS, NB);
  hipLaunchKernelGGL(k4_core1, dim3(16), dim3(256), 0, stream, E_a, E_b, h_idx, Wm,
                     g0r, b0r, g0i, b0i, traw);
  hipLaunchKernelGGL(k5_core2, dim3(1), dim3(256), 0, stream, traw, R_re, R_im, r_idx,
                     g1r, b1r, g1i, b1i, t01);
  hipLaunchKernelGGL(k6_v, dim3(40, 16, 2), dim3(256), 0, stream, Wm, G, P);
  hipLaunchKernelGGL(k7_stats, dim3(100, 2), dim3(256), 0, stream, P, Wm, CS,
                     gEa, bEa, gEb, bEb, alpha, beta);
  hipLaunchKernelGGL(k8_u, dim3(16), dim3(128), 0, stream, t01, alpha, beta, Wm, u, c);
  hipLaunchKernelGGL(k9_score, dim3((NE + 255) / 256), dim3(256), 0, stream,
                     E_a, E_b, u, c, out);
}

// Round 3
// 155.985 us; speedup vs baseline: 1.9831x; 1.9831x over previous
//
#include <hip/hip_runtime.h>
#include <math.h>

#define D100 100
#define NE 50000
#define BATCH 16
#define EPS_F 1e-5f
#define NB_MAX 360
#define SLICES 16

// ---------------------------------------------------------------------------
// K1 fallback (monolithic): Wm[t][b][e][f] = sum_k R2[r_idx[b]][k] * W_t[k][e][f]
__global__ void k1_wm(const float* __restrict__ W_re, const float* __restrict__ W_im,
                      const float* __restrict__ R2, const int* __restrict__ r_idx,
                      float* __restrict__ Wm) {
  const int t = blockIdx.y;
  const float* W = t ? W_im : W_re;
  int ef = blockIdx.x * 256 + threadIdx.x;
  if (ef >= 10000) return;
  int ridx[16];
#pragma unroll
  for (int b = 0; b < 16; b++) ridx[b] = r_idx[b];
  float acc[16];
#pragma unroll
  for (int b = 0; b < 16; b++) acc[b] = 0.f;
  for (int k = 0; k < 100; k++) {
    float w = W[k * 10000 + ef];
#pragma unroll
    for (int b = 0; b < 16; b++) acc[b] = fmaf(R2[ridx[b] * 100 + k], w, acc[b]);
  }
  float* o = Wm + t * 160000 + ef;
#pragma unroll
  for (int b = 0; b < 16; b++) o[b * 10000] = acc[b];
}

// ---------------------------------------------------------------------------
// K1a: split-K partials. grid (10, 4, 2), block 256
__global__ void k1a_wm(const float* __restrict__ W_re, const float* __restrict__ W_im,
                       const float* __restrict__ R2, const int* __restrict__ r_idx,
                       float* __restrict__ Wm_p) {
  const int t = blockIdx.z, kc = blockIdx.y;
  const float* W = t ? W_im : W_re;
  const float4* W4 = (const float4*)W;
  __shared__ float r2s[16][28];
  const int tid = threadIdx.x;
  for (int i = tid; i < 400; i += 256) {
    int b = i / 25, kk = i - b * 25;
    r2s[b][kk] = R2[r_idx[b] * 100 + kc * 25 + kk];
  }
  __syncthreads();
  int ef4 = blockIdx.x * 256 + tid;
  if (ef4 < 2500) {
    float4 acc[16];
#pragma unroll
    for (int b = 0; b < 16; b++) acc[b] = make_float4(0.f, 0.f, 0.f, 0.f);
#pragma unroll 5
    for (int kk = 0; kk < 25; kk++) {
      float4 w = W4[(kc * 25 + kk) * 2500 + ef4];
#pragma unroll
      for (int b = 0; b < 16; b++) {
        float r = r2s[b][kk];
        acc[b].x = fmaf(r, w.x, acc[b].x);
        acc[b].y = fmaf(r, w.y, acc[b].y);
        acc[b].z = fmaf(r, w.z, acc[b].z);
        acc[b].w = fmaf(r, w.w, acc[b].w);
      }
    }
    float4* o = (float4*)(Wm_p + (long)kc * 320000 + t * 160000);
#pragma unroll
    for (int b = 0; b < 16; b++) o[b * 2500 + ef4] = acc[b];
  }
}

// K1b: Wm = sum over 4 kc partials.  grid (313), block 256 (float4 elements)
__global__ void k1b_reduce(const float* __restrict__ Wm_p, float* __restrict__ Wm) {
  int i4 = blockIdx.x * 256 + threadIdx.x;
  if (i4 >= 80000) return;
  const float4* P4 = (const float4*)Wm_p;
  float4 a = P4[i4], b = P4[80000 + i4], c = P4[160000 + i4], d = P4[240000 + i4];
  float4 o;
  o.x = a.x + b.x + c.x + d.x;
  o.y = a.y + b.y + c.y + d.y;
  o.z = a.z + b.z + c.z + d.z;
  o.w = a.w + b.w + c.w + d.w;
  ((float4*)Wm)[i4] = o;
}

// ---------------------------------------------------------------------------
// K2: block-partial Gram G = E^T E, double-buffered LDS, 8x8 register tiles
// grid (NB, 2), block 256
__global__ __launch_bounds__(256, 4) void k2_gram(const float* __restrict__ E_a,
                                                  const float* __restrict__ E_b,
                                                  float* __restrict__ Gp,
                                                  float* __restrict__ CSp,
                                                  int NB, int RPB) {
  const int t = blockIdx.y;
  const float* E = t ? E_b : E_a;
  const float4* E4 = (const float4*)E;
  __shared__ float sm[2][32][128];
  const int tid = threadIdx.x;
  const int bx = blockIdx.x;
  int r0 = bx * RPB;
  int rend = min(r0 + RPB, NE);

  for (int i = tid; i < 2 * 32 * 28; i += 256) {
    int buf = i / (32 * 28);
    int rem = i - buf * (32 * 28);
    int r = rem / 28;
    sm[buf][r][100 + (rem - r * 28)] = 0.f;
  }

  float4 st[4];
#define LOAD_CHUNK(base)                                     \
  {                                                          \
    _Pragma("unroll")                                        \
    for (int s = 0; s < 4; s++) {                            \
      int i = s * 256 + tid;                                 \
      float4 v = make_float4(0.f, 0.f, 0.f, 0.f);            \
      if (i < 800) {                                         \
        int r = i / 25, c4 = i - r * 25;                     \
        int row = (base) + r;                                \
        if (row < rend) v = E4[row * 25 + c4];               \
      }                                                      \
      st[s] = v;                                             \
    }                                                        \
  }
#define WRITE_CHUNK(buf)                                     \
  {                                                          \
    _Pragma("unroll")                                        \
    for (int s = 0; s < 4; s++) {                            \
      int i = s * 256 + tid;                                 \
      if (i < 800) {                                         \
        int r = i / 25, c4 = i - r * 25;                     \
        *(float4*)&sm[buf][r][c4 * 4] = st[s];               \
      }                                                      \
    }                                                        \
  }

  float acc[8][8];
#pragma unroll
  for (int i = 0; i < 8; i++)
#pragma unroll
    for (int j = 0; j < 8; j++) acc[i][j] = 0.f;
  float cs = 0.f;
  const int ty = tid >> 4, tx = tid & 15;

  LOAD_CHUNK(r0);
  WRITE_CHUNK(0);
  __syncthreads();
  int nch = (rend - r0 + 31) / 32;
  for (int c = 0; c < nch; c++) {
    int buf = c & 1;
    if (c + 1 < nch) LOAD_CHUNK(r0 + (c + 1) * 32);
#pragma unroll 2
    for (int r = 0; r < 32; r++) {
      float4 a0 = *(const float4*)&sm[buf][r][ty * 8];
      float4 a1 = *(const float4*)&sm[buf][r][ty * 8 + 4];
      float4 b0 = *(const float4*)&sm[buf][r][tx * 8];
      float4 b1 = *(const float4*)&sm[buf][r][tx * 8 + 4];
      float av[8] = {a0.x, a0.y, a0.z, a0.w, a1.x, a1.y, a1.z, a1.w};
      float bv[8] = {b0.x, b0.y, b0.z, b0.w, b1.x, b1.y, b1.z, b1.w};
#pragma unroll
      for (int i = 0; i < 8; i++)
#pragma unroll
        for (int j = 0; j < 8; j++) acc[i][j] = fmaf(av[i], bv[j], acc[i][j]);
    }
    if (tid < 100) {
#pragma unroll 4
      for (int r = 0; r < 32; r++) cs += sm[buf][r][tid];
    }
    __syncthreads();
    if (c + 1 < nch) {
      WRITE_CHUNK(buf ^ 1);
      __syncthreads();
    }
  }

  float* gp = Gp + (t * NB + bx) * 10000;
#pragma unroll
  for (int i = 0; i < 8; i++) {
    int e = ty * 8 + i;
    if (e < 100) {
#pragma unroll
      for (int j = 0; j < 8; j++) {
        int ep = tx * 8 + j;
        if (ep < 100) gp[e * 100 + ep] = acc[i][j];
      }
    }
  }
  if (tid < 100) CSp[(t * NB + bx) * 100 + tid] = cs;
}

// ---------------------------------------------------------------------------
// K3a: tree-reduce stage A.  grid (40, SLICES, 2), block 256.
// Each block sums `seg` Gram partials for its 256-wide idx chunk.
__global__ void k3a_reduce(const float* __restrict__ Gp, const float* __restrict__ CSp,
                           float* __restrict__ Gp2, float* __restrict__ CSp2,
                           int NB, int seg) {
  int chunk = blockIdx.x, slice = blockIdx.y, t = blockIdx.z;
  int nb0 = slice * seg;
  int nb1 = min(nb0 + seg, NB);
  int idx = chunk * 256 + threadIdx.x;
  if (idx < 10000) {
    float s = 0.f;
    const float* p = Gp + ((long)t * NB + nb0) * 10000 + idx;
    for (int nb = nb0; nb < nb1; nb++, p += 10000) s += *p;
    Gp2[(t * SLICES + slice) * 10000 + idx] = s;
  }
  if (chunk == 0 && threadIdx.x < 100) {
    float s = 0.f;
    const float* p = CSp + ((long)t * NB + nb0) * 100 + threadIdx.x;
    for (int nb = nb0; nb < nb1; nb++, p += 100) s += *p;
    CSp2[(t * SLICES + slice) * 100 + threadIdx.x] = s;
  }
}

// K3b: tree-reduce stage B.  grid (40, 2), block 256.
__global__ void k3b_reduce(const float* __restrict__ Gp2, const float* __restrict__ CSp2,
                           float* __restrict__ G, float* __restrict__ CS) {
  int chunk = blockIdx.x, t = blockIdx.y;
  int idx = chunk * 256 + threadIdx.x;
  if (idx < 10000) {
    float s = 0.f;
    const float* p = Gp2 + (long)t * SLICES * 10000 + idx;
#pragma unroll
    for (int sl = 0; sl < SLICES; sl++) s += p[sl * 10000];
    G[t * 10000 + idx] = s;
  }
  if (chunk == 0 && threadIdx.x < 100) {
    float s = 0.f;
    const float* p = CSp2 + (long)t * SLICES * 100 + threadIdx.x;
#pragma unroll
    for (int sl = 0; sl < SLICES; sl++) s += p[sl * 100];
    CS[t * 100 + threadIdx.x] = s;
  }
}

// ---------------------------------------------------------------------------
// K4: gather h, BN2 over batch, per-batch matvec with Wm -> traw.  grid (16), block 256
__global__ void k4_core1(const float* __restrict__ E_a, const float* __restrict__ E_b,
                         const int* __restrict__ h_idx, const float* __restrict__ Wm,
                         const float* __restrict__ g0r, const float* __restrict__ b0r,
                         const float* __restrict__ g0i, const float* __restrict__ b0i,
                         float* __restrict__ traw) {
  __shared__ float ha[1600], hb[1600], xa[100], xb[100];
  int tid = threadIdx.x, bo = blockIdx.x;
  for (int idx = tid; idx < 1600; idx += 256) {
    int bb = idx / 100, e = idx - bb * 100;
    int h = h_idx[bb];
    ha[idx] = E_a[h * 100 + e];
    hb[idx] = E_b[h * 100 + e];
  }
  __syncthreads();
  if (tid < 100) {
    float m = 0.f, s = 0.f;
#pragma unroll
    for (int b = 0; b < 16; b++) { float v = ha[b * 100 + tid]; m += v; s += v * v; }
    m *= (1.f / 16.f);
    float var = s * (1.f / 16.f) - m * m;
    xa[tid] = (ha[bo * 100 + tid] - m) * rsqrtf(var + EPS_F) * g0r[tid] + b0r[tid];
    m = 0.f; s = 0.f;
#pragma unroll
    for (int b = 0; b < 16; b++) { float v = hb[b * 100 + tid]; m += v; s += v * v; }
    m *= (1.f / 16.f);
    var = s * (1.f / 16.f) - m * m;
    xb[tid] = (hb[bo * 100 + tid] - m) * rsqrtf(var + EPS_F) * g0i[tid] + b0i[tid];
  }
  __syncthreads();
  if (tid < 100) {
    float sa = 0.f, sb = 0.f;
    const float* wa = Wm + bo * 10000 + tid;
    const float* wb = Wm + 160000 + bo * 10000 + tid;
    for (int e = 0; e < 100; e++) {
      sa = fmaf(xa[e], wa[e * 100], sa);
      sb = fmaf(xb[e], wb[e * 100], sb);
    }
    traw[bo * 100 + tid] = sa;
    traw[1600 + bo * 100 + tid] = sb;
  }
}

// ---------------------------------------------------------------------------
// K5: BN2 of traw + Mobius -> t0,t1.  grid(1), block 256
__global__ void k5_core2(const float* __restrict__ traw,
                         const float* __restrict__ R_re, const float* __restrict__ R_im,
                         const int* __restrict__ r_idx,
                         const float* __restrict__ g1r, const float* __restrict__ b1r,
                         const float* __restrict__ g1i, const float* __restrict__ b1i,
                         float* __restrict__ t01) {
  __shared__ float ta[1600], tb[1600], sca[100], sha[100], scb[100], shb[100];
  int tid = threadIdx.x;
  for (int i = tid; i < 1600; i += 256) { ta[i] = traw[i]; tb[i] = traw[1600 + i]; }
  __syncthreads();
  if (tid < 100) {
    float m = 0.f, s = 0.f;
#pragma unroll
    for (int b = 0; b < 16; b++) { float v = ta[b * 100 + tid]; m += v; s += v * v; }
    m *= (1.f / 16.f);
    float var = s * (1.f / 16.f) - m * m;
    float sc = rsqrtf(var + EPS_F) * g1r[tid];
    sca[tid] = sc; sha[tid] = b1r[tid] - m * sc;
    m = 0.f; s = 0.f;
#pragma unroll
    for (int b = 0; b < 16; b++) { float v = tb[b * 100 + tid]; m += v; s += v * v; }
    m *= (1.f / 16.f);
    var = s * (1.f / 16.f) - m * m;
    sc = rsqrtf(var + EPS_F) * g1i[tid];
    scb[tid] = sc; shb[tid] = b1i[tid] - m * sc;
  }
  __syncthreads();
  for (int idx = tid; idx < 1600; idx += 256) {
    int b = idx / 100, f = idx - b * 100;
    float va = ta[idx] * sca[f] + sha[f];
    float vb = tb[idx] * scb[f] + shb[f];
    int base = r_idx[b] * 400 + f;
    float ra0 = R_re[base],       ra1 = R_im[base];
    float rb0 = R_re[base + 100], rb1 = R_im[base + 100];
    float rc0 = R_re[base + 200], rc1 = R_im[base + 200];
    float rd0 = R_re[base + 300], rd1 = R_im[base + 300];
    float top0 = va * ra0 - vb * ra1 + rb0;
    float top1 = va * ra1 + vb * ra0 + rb1;
    float bot0 = va * rc0 - vb * rc1 + rd0;
    float bot1 = va * rc1 + vb * rc0 + rd1;
    float den = bot0 * bot0 + bot1 * bot1;
    t01[idx]        = (top0 * bot0 + top1 * bot1) / den;
    t01[1600 + idx] = (top1 * bot0 - top0 * bot1) / den;
  }
}

// ---------------------------------------------------------------------------
// K6: P[t][b][ep][f] = (sum_e Wm[t][b][e][f] * G[t][e][ep]) * Wm[t][b][ep][f]
// grid (40, 16, 2), block 256
__global__ void k6_v(const float* __restrict__ Wm, const float* __restrict__ G,
                     float* __restrict__ P) {
  int t = blockIdx.z, b = blockIdx.y;
  int ef = blockIdx.x * 256 + threadIdx.x;
  if (ef >= 10000) return;
  int ep = ef / 100, f = ef - ep * 100;
  const float* Wmt = Wm + t * 160000 + b * 10000;
  const float* Gt = G + t * 10000 + ep;
  float a = 0.f;
  for (int e = 0; e < 100; e++) a = fmaf(Wmt[e * 100 + f], Gt[e * 100], a);
  P[t * 160000 + b * 10000 + ef] = a * Wmt[ep * 100 + f];
}

// ---------------------------------------------------------------------------
// K7: per-f BN3 stats -> alpha,beta.  grid (100, 2), block 256
__global__ void k7_stats(const float* __restrict__ P, const float* __restrict__ Wm,
                         const float* __restrict__ CS,
                         const float* __restrict__ gEa, const float* __restrict__ bEa,
                         const float* __restrict__ gEb, const float* __restrict__ bEb,
                         float* __restrict__ alpha, float* __restrict__ beta) {
  int f = blockIdx.x, t = blockIdx.y, tid = threadIdx.x;
  __shared__ float r1[256], r2[256];
  float s1 = 0.f, s2 = 0.f;
  const float* Pp = P + t * 160000 + f;
  const float* Wp = Wm + t * 160000 + f;
  const float* csp = CS + t * 100;
  for (int p = tid; p < 1600; p += 256) {
    s1 += Pp[p * 100];
    int e = p - (p / 100) * 100;
    s2 += Wp[p * 100] * csp[e];
  }
  r1[tid] = s1; r2[tid] = s2;
  __syncthreads();
  for (int o = 128; o > 0; o >>= 1) {
    if (tid < o) { r1[tid] += r1[tid + o]; r2[tid] += r2[tid + o]; }
    __syncthreads();
  }
  if (tid == 0) {
    float mean = r2[0] * (1.f / 800000.f);
    float var = r1[0] * (1.f / 800000.f) - mean * mean;
    float g = t ? gEb[f] : gEa[f];
    float bb = t ? bEb[f] : bEa[f];
    float al = rsqrtf(var + EPS_F) * g;
    alpha[t * 100 + f] = al;
    beta[t * 100 + f] = bb - mean * al;
  }
}

// ---------------------------------------------------------------------------
// K8: u, c.  grid (16), block 128
__global__ void k8_u(const float* __restrict__ t01, const float* __restrict__ alpha,
                     const float* __restrict__ beta, const float* __restrict__ Wm,
                     float* __restrict__ u, float* __restrict__ c) {
  int b = blockIdx.x, tid = threadIdx.x;
  __shared__ float w0[100], w1[100], pc[128];
  float p = 0.f;
  if (tid < 100) {
    float t0 = t01[b * 100 + tid], t1 = t01[1600 + b * 100 + tid];
    w0[tid] = t0 * alpha[tid];
    w1[tid] = t1 * alpha[100 + tid];
    p = t0 * beta[tid] + t1 * beta[100 + tid];
  }
  pc[tid] = (tid < 100) ? p : 0.f;
  __syncthreads();
  for (int o = 64; o > 0; o >>= 1) {
    if (tid < o) pc[tid] += pc[tid + o];
    __syncthreads();
  }
  if (tid == 0) c[b] = pc[0];
  if (tid < 100) {
    float sa = 0.f, sb = 0.f;
    const float* wa = Wm + b * 10000 + tid * 100;
    const float* wb = Wm + 160000 + b * 10000 + tid * 100;
    for (int f = 0; f < 100; f++) {
      sa = fmaf(w0[f], wa[f], sa);
      sb = fmaf(w1[f], wb[f], sb);
    }
    u[tid * 16 + b] = sa;
    u[(100 + tid) * 16 + b] = sb;
  }
}

// ---------------------------------------------------------------------------
// K9: score = sigmoid(c + u_a·E_a + u_b·E_b).  grid (196), block 256
__device__ __forceinline__ float f4get(const float4& v, int j) {
  switch (j) { case 0: return v.x; case 1: return v.y; case 2: return v.z; default: return v.w; }
}

__global__ __launch_bounds__(256) void k9_score(const float* __restrict__ E_a,
                                                const float* __restrict__ E_b,
                                                const float* __restrict__ u,
                                                const float* __restrict__ c,
                                                float* __restrict__ out) {
  int n = blockIdx.x * 256 + threadIdx.x;
  if (n >= NE) return;
  const float4* Ea4 = (const float4*)E_a;
  const float4* Eb4 = (const float4*)E_b;
  float acc[16];
#pragma unroll
  for (int b = 0; b < 16; b++) acc[b] = 0.f;
  for (int e4 = 0; e4 < 25; e4++) {
    float4 va = Ea4[n * 25 + e4];
    float4 vb = Eb4[n * 25 + e4];
    const float* ua = u + e4 * 64;
    const float* ub = u + 1600 + e4 * 64;
#pragma unroll
    for (int j = 0; j < 4; j++) {
      float fa = f4get(va, j);
      float fb = f4get(vb, j);
#pragma unroll
      for (int b = 0; b < 16; b++) {
        acc[b] = fmaf(ua[j * 16 + b], fa, acc[b]);
        acc[b] = fmaf(ub[j * 16 + b], fb, acc[b]);
      }
    }
  }
#pragma unroll
  for (int b = 0; b < 16; b++) {
    float x = acc[b] + c[b];
    out[b * NE + n] = 1.f / (1.f + expf(-x));
  }
}

// ---------------------------------------------------------------------------
extern "C" void kernel_launch(void* const* d_in, const int* in_sizes, int n_in,
                              void* d_out, int out_size, void* d_ws, size_t ws_size,
                              hipStream_t stream) {
  const int* h_idx = (const int*)d_in[0];
  const int* r_idx = (const int*)d_in[1];
  const float* E_a = (const float*)d_in[2];
  const float* E_b = (const float*)d_in[3];
  const float* R_re = (const float*)d_in[4];
  const float* R_im = (const float*)d_in[5];
  const float* R2 = (const float*)d_in[6];
  const float* W_re = (const float*)d_in[7];
  const float* W_im = (const float*)d_in[8];
  const float* g0r = (const float*)d_in[9];
  const float* b0r = (const float*)d_in[10];
  const float* g1r = (const float*)d_in[11];
  const float* b1r = (const float*)d_in[12];
  const float* g0i = (const float*)d_in[13];
  const float* b0i = (const float*)d_in[14];
  const float* g1i = (const float*)d_in[15];
  const float* b1i = (const float*)d_in[16];
  const float* gEa = (const float*)d_in[17];
  const float* bEa = (const float*)d_in[18];
  const float* gEb = (const float*)d_in[19];
  const float* bEb = (const float*)d_in[20];
  float* out = (float*)d_out;
  float* ws = (float*)d_ws;

  // fixed regions (350,216 floats)
  float* Wm = ws;                  // [2][16][10000]   320000
  float* G = Wm + 320000;          // [2][10000]        20000
  float* CS = G + 20000;           // [2][100]            200
  float* traw = CS + 200;          // [2][16][100]       3200
  float* t01 = traw + 3200;        // [2][16][100]       3200
  float* alpha = t01 + 3200;       //                     200
  float* beta = alpha + 200;       //                     200
  float* u = beta + 200;           // [2][100][16]       3200
  float* c = u + 3200;             //                      16
  const long fixed = 350216;

  // union region: Wm_p (k1a->k1b), {Gp2,CSp2,Gp,CSp} (k2->k3a->k3b),
  // P (k6->k7) have pairwise-disjoint active lifetimes on the serial stream.
  float* un = ws + fixed;
  long avail = (long)(ws_size / 4);
  long unionFloats = avail - fixed - 64;

  float* Gp2 = un;                      // [2][SLICES][10000]  320000
  float* CSp2 = Gp2 + 320000;           // [2][SLICES][100]      3200
  float* Gp = CSp2 + 3200;              // [2][NB][10000]
  const long per_nb = 2 * 10000 + 2 * 100;
  int NB = NB_MAX;
  long room = (unionFloats - 323200) / per_nb;
  if (room < NB) NB = (int)room;
  if (NB < 1) NB = 1;
  int RPB = (NE + NB - 1) / NB;
  int seg = (NB + SLICES - 1) / SLICES;
  float* CSp = Gp + (long)NB * 20000;   // [2][NB][100]

  float* P = un;                        // [2][16][10000] (after k3b done)
  float* Wm_p = un;                     // [4][2][16][10000] = 1,280,000
  int splitK1 = (unionFloats >= 1280000);

  if (splitK1) {
    hipLaunchKernelGGL(k1a_wm, dim3(10, 4, 2), dim3(256), 0, stream, W_re, W_im, R2, r_idx, Wm_p);
    hipLaunchKernelGGL(k1b_reduce, dim3(313), dim3(256), 0, stream, Wm_p, Wm);
  } else {
    hipLaunchKernelGGL(k1_wm, dim3(40, 2), dim3(256), 0, stream, W_re, W_im, R2, r_idx, Wm);
  }
  hipLaunchKernelGGL(k2_gram, dim3(NB, 2), dim3(256), 0, stream, E_a, E_b, Gp, CSp, NB, RPB);
  hipLaunchKernelGGL(k3a_reduce, dim3(40, SLICES, 2), dim3(256), 0, stream,
                     Gp, CSp, Gp2, CSp2, NB, seg);
  hipLaunchKernelGGL(k3b_reduce, dim3(40, 2), dim3(256), 0, stream, Gp2, CSp2, G, CS);
  hipLaunchKernelGGL(k4_core1, dim3(16), dim3(256), 0, stream, E_a, E_b, h_idx, Wm,
                     g0r, b0r, g0i, b0i, traw);
  hipLaunchKernelGGL(k5_core2, dim3(1), dim3(256), 0, stream, traw, R_re, R_im, r_idx,
                     g1r, b1r, g1i, b1i, t01);
  hipLaunchKernelGGL(k6_v, dim3(40, 16, 2), dim3(256), 0, stream, Wm, G, P);
  hipLaunchKernelGGL(k7_stats, dim3(100, 2), dim3(256), 0, stream, P, Wm, CS,
                     gEa, bEa, gEb, bEb, alpha, beta);
  hipLaunchKernelGGL(k8_u, dim3(16), dim3(128), 0, stream, t01, alpha, beta, Wm, u, c);
  hipLaunchKernelGGL(k9_score, dim3((NE + 255) / 256), dim3(256), 0, stream,
                     E_a, E_b, u, c, out);
}

// Round 4
// 126.600 us; speedup vs baseline: 2.4434x; 1.2321x over previous
//
#include <hip/hip_runtime.h>
#include <math.h>

#define D100 100
#define NE 50000
#define BATCH 16
#define EPS_F 1e-5f
#define NPAD 50016           // 50000 rounded up to multiple of 32, zero-padded
#define SLICES 16

typedef __attribute__((ext_vector_type(8))) short short8;
typedef __attribute__((ext_vector_type(16))) float float16;
typedef unsigned short u16;

__device__ __forceinline__ u16 f2bf(float x) {   // RNE float->bf16
  union { float f; unsigned u; } c; c.f = x;
  unsigned r = c.u + 0x7FFFu + ((c.u >> 16) & 1u);
  return (u16)(r >> 16);
}
__device__ __forceinline__ float bf2f(u16 v) {
  return __uint_as_float(((unsigned)v) << 16);
}

// ---------------------------------------------------------------------------
// K1 fallback (monolithic)
__global__ void k1_wm(const float* __restrict__ W_re, const float* __restrict__ W_im,
                      const float* __restrict__ R2, const int* __restrict__ r_idx,
                      float* __restrict__ Wm) {
  const int t = blockIdx.y;
  const float* W = t ? W_im : W_re;
  int ef = blockIdx.x * 256 + threadIdx.x;
  if (ef >= 10000) return;
  int ridx[16];
#pragma unroll
  for (int b = 0; b < 16; b++) ridx[b] = r_idx[b];
  float acc[16];
#pragma unroll
  for (int b = 0; b < 16; b++) acc[b] = 0.f;
  for (int k = 0; k < 100; k++) {
    float w = W[k * 10000 + ef];
#pragma unroll
    for (int b = 0; b < 16; b++) acc[b] = fmaf(R2[ridx[b] * 100 + k], w, acc[b]);
  }
  float* o = Wm + t * 160000 + ef;
#pragma unroll
  for (int b = 0; b < 16; b++) o[b * 10000] = acc[b];
}

// ---------------------------------------------------------------------------
// K1a: split-K partials. grid (10, 4, 2), block 256
__global__ void k1a_wm(const float* __restrict__ W_re, const float* __restrict__ W_im,
                       const float* __restrict__ R2, const int* __restrict__ r_idx,
                       float* __restrict__ Wm_p) {
  const int t = blockIdx.z, kc = blockIdx.y;
  const float* W = t ? W_im : W_re;
  const float4* W4 = (const float4*)W;
  __shared__ float r2s[16][28];
  const int tid = threadIdx.x;
  for (int i = tid; i < 400; i += 256) {
    int b = i / 25, kk = i - b * 25;
    r2s[b][kk] = R2[r_idx[b] * 100 + kc * 25 + kk];
  }
  __syncthreads();
  int ef4 = blockIdx.x * 256 + tid;
  if (ef4 < 2500) {
    float4 acc[16];
#pragma unroll
    for (int b = 0; b < 16; b++) acc[b] = make_float4(0.f, 0.f, 0.f, 0.f);
#pragma unroll 5
    for (int kk = 0; kk < 25; kk++) {
      float4 w = W4[(kc * 25 + kk) * 2500 + ef4];
#pragma unroll
      for (int b = 0; b < 16; b++) {
        float r = r2s[b][kk];
        acc[b].x = fmaf(r, w.x, acc[b].x);
        acc[b].y = fmaf(r, w.y, acc[b].y);
        acc[b].z = fmaf(r, w.z, acc[b].z);
        acc[b].w = fmaf(r, w.w, acc[b].w);
      }
    }
    float4* o = (float4*)(Wm_p + (long)kc * 320000 + t * 160000);
#pragma unroll
    for (int b = 0; b < 16; b++) o[b * 2500 + ef4] = acc[b];
  }
}

// K1b: Wm = sum over 4 kc partials.  grid (313), block 256
__global__ void k1b_reduce(const float* __restrict__ Wm_p, float* __restrict__ Wm) {
  int i4 = blockIdx.x * 256 + threadIdx.x;
  if (i4 >= 80000) return;
  const float4* P4 = (const float4*)Wm_p;
  float4 a = P4[i4], b = P4[80000 + i4], c = P4[160000 + i4], d = P4[240000 + i4];
  float4 o;
  o.x = a.x + b.x + c.x + d.x;
  o.y = a.y + b.y + c.y + d.y;
  o.z = a.z + b.z + c.z + d.z;
  o.w = a.w + b.w + c.w + d.w;
  ((float4*)Wm)[i4] = o;
}

// ---------------------------------------------------------------------------
// K2t: transpose + cast: E[t] (50000x100 f32) -> ET[t] (100 x NPAD bf16, 0-padded)
// grid (782, 2), block 256
__global__ __launch_bounds__(256) void k2t_transpose(const float* __restrict__ E_a,
                                                     const float* __restrict__ E_b,
                                                     u16* __restrict__ ET) {
  const int t = blockIdx.y;
  const float4* E4 = (const float4*)(t ? E_b : E_a);
  u16* T = ET + (long)t * 100 * NPAD;
  __shared__ u16 Tl[64][106];
  const int tid = threadIdx.x;
  const int n0 = blockIdx.x * 64;
  for (int i = tid; i < 1600; i += 256) {
    int n = i / 25, e4 = i - n * 25;
    float4 v = make_float4(0.f, 0.f, 0.f, 0.f);
    if (n0 + n < NE) v = E4[(long)(n0 + n) * 25 + e4];
    ushort2 lo, hi;
    lo.x = f2bf(v.x); lo.y = f2bf(v.y);
    hi.x = f2bf(v.z); hi.y = f2bf(v.w);
    *(ushort2*)&Tl[n][e4 * 4] = lo;
    *(ushort2*)&Tl[n][e4 * 4 + 2] = hi;
  }
  __syncthreads();
  for (int i = tid; i < 800; i += 256) {
    int e = i >> 3, g = i & 7;
    int n = n0 + g * 8;
    if (n < NPAD) {
      ushort4 w0, w1;
      w0.x = Tl[g * 8 + 0][e]; w0.y = Tl[g * 8 + 1][e];
      w0.z = Tl[g * 8 + 2][e]; w0.w = Tl[g * 8 + 3][e];
      w1.x = Tl[g * 8 + 4][e]; w1.y = Tl[g * 8 + 5][e];
      w1.z = Tl[g * 8 + 6][e]; w1.w = Tl[g * 8 + 7][e];
      *(ushort4*)&T[(long)e * NPAD + n] = w0;
      *(ushort4*)&T[(long)e * NPAD + n + 4] = w1;
    }
  }
}

// ---------------------------------------------------------------------------
// K2g: MFMA Gram partials from ET.  grid (NB, 2), block 256 (4 waves).
// Wave w owns output rows [32w,32w+32) x cols [0,128) as 4x mfma_f32_32x32x16_bf16.
// A/B frag layouts coincide for E^T E: lane&31 = row/col, (lane>>5)*8 = k-octet.
__global__ __launch_bounds__(256) void k2g_mfma(const u16* __restrict__ ET,
                                                float* __restrict__ Gp,
                                                float* __restrict__ CSp,
                                                int NB, int RPB) {
  const int t = blockIdx.y, bx = blockIdx.x;
  const u16* T = ET + (long)t * 100 * NPAD;
  const int n0 = bx * RPB;
  const int n1 = min(n0 + RPB, NPAD);
  const int tid = threadIdx.x, wave = tid >> 6, lane = tid & 63;
  const int l31 = lane & 31, kg = (lane >> 5) * 8;
  const int rowA = wave * 32 + l31;
  const bool va = rowA < 100;
  const bool vb3 = (96 + l31) < 100;
  const u16* pa = T + (long)rowA * NPAD + kg;
  const u16* pb0 = T + (long)l31 * NPAD + kg;
  const u16* pb1 = T + (long)(32 + l31) * NPAD + kg;
  const u16* pb2 = T + (long)(64 + l31) * NPAD + kg;
  const u16* pb3 = T + (long)(96 + l31) * NPAD + kg;
  const short8 z8 = {0, 0, 0, 0, 0, 0, 0, 0};
  float16 acc0, acc1, acc2, acc3;
#pragma unroll 16
  for (int r = 0; r < 16; r++) { acc0[r] = 0.f; acc1[r] = 0.f; acc2[r] = 0.f; acc3[r] = 0.f; }

#pragma unroll 2
  for (int n = n0; n < n1; n += 16) {
    short8 a = va ? *(const short8*)(pa + n) : z8;
    short8 b0 = *(const short8*)(pb0 + n);
    short8 b1 = *(const short8*)(pb1 + n);
    short8 b2 = *(const short8*)(pb2 + n);
    short8 b3 = vb3 ? *(const short8*)(pb3 + n) : z8;
    acc0 = __builtin_amdgcn_mfma_f32_32x32x16_bf16(a, b0, acc0, 0, 0, 0);
    acc1 = __builtin_amdgcn_mfma_f32_32x32x16_bf16(a, b1, acc1, 0, 0, 0);
    acc2 = __builtin_amdgcn_mfma_f32_32x32x16_bf16(a, b2, acc2, 0, 0, 0);
    acc3 = __builtin_amdgcn_mfma_f32_32x32x16_bf16(a, b3, acc3, 0, 0, 0);
  }

  float* gp = Gp + ((long)t * NB + bx) * 10000;
#pragma unroll 16
  for (int r = 0; r < 16; r++) {
    int m = (r & 3) + 8 * (r >> 2) + 4 * (lane >> 5);   // verified C/D mapping
    int e = wave * 32 + m;
    if (e < 100) {
      gp[e * 100 + l31] = acc0[r];
      gp[e * 100 + 32 + l31] = acc1[r];
      gp[e * 100 + 64 + l31] = acc2[r];
      if (vb3) gp[e * 100 + 96 + l31] = acc3[r];
    }
  }

  // colsum partial over [n0,n1) (bf16 rows, L2-hot)
  if (tid < 100) {
    const u16* pr = T + (long)tid * NPAD;
    float cs = 0.f;
    for (int n = n0; n < n1; n += 8) {
      short8 v = *(const short8*)(pr + n);
#pragma unroll 8
      for (int k = 0; k < 8; k++) cs += bf2f((u16)v[k]);
    }
    CSp[((long)t * NB + bx) * 100 + tid] = cs;
  }
}

// ---------------------------------------------------------------------------
// K2 fallback: VALU Gram (only if workspace too small for ET)
__global__ __launch_bounds__(256, 4) void k2_gram(const float* __restrict__ E_a,
                                                  const float* __restrict__ E_b,
                                                  float* __restrict__ Gp,
                                                  float* __restrict__ CSp,
                                                  int NB, int RPB) {
  const int t = blockIdx.y;
  const float* E = t ? E_b : E_a;
  const float4* E4 = (const float4*)E;
  __shared__ float sm[32][128];
  const int tid = threadIdx.x;
  const int bx = blockIdx.x;
  int r0 = bx * RPB;
  int rend = min(r0 + RPB, NE);
  for (int i = tid; i < 32 * 28; i += 256) {
    int r = i / 28;
    sm[r][100 + (i - r * 28)] = 0.f;
  }
  float acc[8][8];
#pragma unroll
  for (int i = 0; i < 8; i++)
#pragma unroll
    for (int j = 0; j < 8; j++) acc[i][j] = 0.f;
  float cs = 0.f;
  const int ty = tid >> 4, tx = tid & 15;
  for (int base = r0; base < rend; base += 32) {
    int cnt = min(32, rend - base);
    __syncthreads();
    for (int i = tid; i < 800; i += 256) {
      int r = i / 25, c4 = i - r * 25;
      float4 v = make_float4(0.f, 0.f, 0.f, 0.f);
      if (r < cnt) v = E4[(long)(base + r) * 25 + c4];
      *(float4*)&sm[r][c4 * 4] = v;
    }
    __syncthreads();
#pragma unroll 2
    for (int r = 0; r < 32; r++) {
      float4 a0 = *(const float4*)&sm[r][ty * 8];
      float4 a1 = *(const float4*)&sm[r][ty * 8 + 4];
      float4 b0 = *(const float4*)&sm[r][tx * 8];
      float4 b1 = *(const float4*)&sm[r][tx * 8 + 4];
      float av[8] = {a0.x, a0.y, a0.z, a0.w, a1.x, a1.y, a1.z, a1.w};
      float bv[8] = {b0.x, b0.y, b0.z, b0.w, b1.x, b1.y, b1.z, b1.w};
#pragma unroll
      for (int i = 0; i < 8; i++)
#pragma unroll
        for (int j = 0; j < 8; j++) acc[i][j] = fmaf(av[i], bv[j], acc[i][j]);
    }
    if (tid < 100) {
#pragma unroll 4
      for (int r = 0; r < 32; r++) cs += sm[r][tid];
    }
  }
  float* gp = Gp + ((long)t * NB + bx) * 10000;
#pragma unroll
  for (int i = 0; i < 8; i++) {
    int e = ty * 8 + i;
    if (e < 100) {
#pragma unroll
      for (int j = 0; j < 8; j++) {
        int ep = tx * 8 + j;
        if (ep < 100) gp[e * 100 + ep] = acc[i][j];
      }
    }
  }
  if (tid < 100) CSp[((long)t * NB + bx) * 100 + tid] = cs;
}

// ---------------------------------------------------------------------------
// K3a/K3b: tree reduce of Gram + colsum partials
__global__ void k3a_reduce(const float* __restrict__ Gp, const float* __restrict__ CSp,
                           float* __restrict__ Gp2, float* __restrict__ CSp2,
                           int NB, int seg) {
  int chunk = blockIdx.x, slice = blockIdx.y, t = blockIdx.z;
  int nb0 = slice * seg;
  int nb1 = min(nb0 + seg, NB);
  int idx = chunk * 256 + threadIdx.x;
  if (idx < 10000) {
    float s = 0.f;
    const float* p = Gp + ((long)t * NB + nb0) * 10000 + idx;
    for (int nb = nb0; nb < nb1; nb++, p += 10000) s += *p;
    Gp2[(t * SLICES + slice) * 10000 + idx] = s;
  }
  if (chunk == 0 && threadIdx.x < 100) {
    float s = 0.f;
    const float* p = CSp + ((long)t * NB + nb0) * 100 + threadIdx.x;
    for (int nb = nb0; nb < nb1; nb++, p += 100) s += *p;
    CSp2[(t * SLICES + slice) * 100 + threadIdx.x] = s;
  }
}

__global__ void k3b_reduce(const float* __restrict__ Gp2, const float* __restrict__ CSp2,
                           float* __restrict__ G, float* __restrict__ CS) {
  int chunk = blockIdx.x, t = blockIdx.y;
  int idx = chunk * 256 + threadIdx.x;
  if (idx < 10000) {
    float s = 0.f;
    const float* p = Gp2 + (long)t * SLICES * 10000 + idx;
#pragma unroll
    for (int sl = 0; sl < SLICES; sl++) s += p[sl * 10000];
    G[t * 10000 + idx] = s;
  }
  if (chunk == 0 && threadIdx.x < 100) {
    float s = 0.f;
    const float* p = CSp2 + (long)t * SLICES * 100 + threadIdx.x;
#pragma unroll
    for (int sl = 0; sl < SLICES; sl++) s += p[sl * 100];
    CS[t * 100 + threadIdx.x] = s;
  }
}

// ---------------------------------------------------------------------------
// K4: gather h, BN2, matvec -> traw.  grid (16), block 256
__global__ void k4_core1(const float* __restrict__ E_a, const float* __restrict__ E_b,
                         const int* __restrict__ h_idx, const float* __restrict__ Wm,
                         const float* __restrict__ g0r, const float* __restrict__ b0r,
                         const float* __restrict__ g0i, const float* __restrict__ b0i,
                         float* __restrict__ traw) {
  __shared__ float ha[1600], hb[1600], xa[100], xb[100];
  int tid = threadIdx.x, bo = blockIdx.x;
  for (int idx = tid; idx < 1600; idx += 256) {
    int bb = idx / 100, e = idx - bb * 100;
    int h = h_idx[bb];
    ha[idx] = E_a[h * 100 + e];
    hb[idx] = E_b[h * 100 + e];
  }
  __syncthreads();
  if (tid < 100) {
    float m = 0.f, s = 0.f;
#pragma unroll
    for (int b = 0; b < 16; b++) { float v = ha[b * 100 + tid]; m += v; s += v * v; }
    m *= (1.f / 16.f);
    float var = s * (1.f / 16.f) - m * m;
    xa[tid] = (ha[bo * 100 + tid] - m) * rsqrtf(var + EPS_F) * g0r[tid] + b0r[tid];
    m = 0.f; s = 0.f;
#pragma unroll
    for (int b = 0; b < 16; b++) { float v = hb[b * 100 + tid]; m += v; s += v * v; }
    m *= (1.f / 16.f);
    var = s * (1.f / 16.f) - m * m;
    xb[tid] = (hb[bo * 100 + tid] - m) * rsqrtf(var + EPS_F) * g0i[tid] + b0i[tid];
  }
  __syncthreads();
  if (tid < 100) {
    float sa = 0.f, sb = 0.f;
    const float* wa = Wm + bo * 10000 + tid;
    const float* wb = Wm + 160000 + bo * 10000 + tid;
    for (int e = 0; e < 100; e++) {
      sa = fmaf(xa[e], wa[e * 100], sa);
      sb = fmaf(xb[e], wb[e * 100], sb);
    }
    traw[bo * 100 + tid] = sa;
    traw[1600 + bo * 100 + tid] = sb;
  }
}

// ---------------------------------------------------------------------------
// K5: BN2 of traw + Mobius -> t0,t1.  grid(1), block 256
__global__ void k5_core2(const float* __restrict__ traw,
                         const float* __restrict__ R_re, const float* __restrict__ R_im,
                         const int* __restrict__ r_idx,
                         const float* __restrict__ g1r, const float* __restrict__ b1r,
                         const float* __restrict__ g1i, const float* __restrict__ b1i,
                         float* __restrict__ t01) {
  __shared__ float ta[1600], tb[1600], sca[100], sha[100], scb[100], shb[100];
  int tid = threadIdx.x;
  for (int i = tid; i < 1600; i += 256) { ta[i] = traw[i]; tb[i] = traw[1600 + i]; }
  __syncthreads();
  if (tid < 100) {
    float m = 0.f, s = 0.f;
#pragma unroll
    for (int b = 0; b < 16; b++) { float v = ta[b * 100 + tid]; m += v; s += v * v; }
    m *= (1.f / 16.f);
    float var = s * (1.f / 16.f) - m * m;
    float sc = rsqrtf(var + EPS_F) * g1r[tid];
    sca[tid] = sc; sha[tid] = b1r[tid] - m * sc;
    m = 0.f; s = 0.f;
#pragma unroll
    for (int b = 0; b < 16; b++) { float v = tb[b * 100 + tid]; m += v; s += v * v; }
    m *= (1.f / 16.f);
    var = s * (1.f / 16.f) - m * m;
    sc = rsqrtf(var + EPS_F) * g1i[tid];
    scb[tid] = sc; shb[tid] = b1i[tid] - m * sc;
  }
  __syncthreads();
  for (int idx = tid; idx < 1600; idx += 256) {
    int b = idx / 100, f = idx - b * 100;
    float va = ta[idx] * sca[f] + sha[f];
    float vb = tb[idx] * scb[f] + shb[f];
    int base = r_idx[b] * 400 + f;
    float ra0 = R_re[base],       ra1 = R_im[base];
    float rb0 = R_re[base + 100], rb1 = R_im[base + 100];
    float rc0 = R_re[base + 200], rc1 = R_im[base + 200];
    float rd0 = R_re[base + 300], rd1 = R_im[base + 300];
    float top0 = va * ra0 - vb * ra1 + rb0;
    float top1 = va * ra1 + vb * ra0 + rb1;
    float bot0 = va * rc0 - vb * rc1 + rd0;
    float bot1 = va * rc1 + vb * rc0 + rd1;
    float den = bot0 * bot0 + bot1 * bot1;
    t01[idx]        = (top0 * bot0 + top1 * bot1) / den;
    t01[1600 + idx] = (top1 * bot0 - top0 * bot1) / den;
  }
}

// ---------------------------------------------------------------------------
// K6: P[t][b][ep][f] = (sum_e Wm[t][b][e][f] * G[t][e][ep]) * Wm[t][b][ep][f]
__global__ void k6_v(const float* __restrict__ Wm, const float* __restrict__ G,
                     float* __restrict__ P) {
  int t = blockIdx.z, b = blockIdx.y;
  int ef = blockIdx.x * 256 + threadIdx.x;
  if (ef >= 10000) return;
  int ep = ef / 100, f = ef - ep * 100;
  const float* Wmt = Wm + t * 160000 + b * 10000;
  const float* Gt = G + t * 10000 + ep;
  float a = 0.f;
  for (int e = 0; e < 100; e++) a = fmaf(Wmt[e * 100 + f], Gt[e * 100], a);
  P[t * 160000 + b * 10000 + ef] = a * Wmt[ep * 100 + f];
}

// ---------------------------------------------------------------------------
// K7: per-f BN3 stats -> alpha,beta.  grid (100, 2), block 256
__global__ void k7_stats(const float* __restrict__ P, const float* __restrict__ Wm,
                         const float* __restrict__ CS,
                         const float* __restrict__ gEa, const float* __restrict__ bEa,
                         const float* __restrict__ gEb, const float* __restrict__ bEb,
                         float* __restrict__ alpha, float* __restrict__ beta) {
  int f = blockIdx.x, t = blockIdx.y, tid = threadIdx.x;
  __shared__ float r1[256], r2[256];
  float s1 = 0.f, s2 = 0.f;
  const float* Pp = P + t * 160000 + f;
  const float* Wp = Wm + t * 160000 + f;
  const float* csp = CS + t * 100;
  for (int p = tid; p < 1600; p += 256) {
    s1 += Pp[p * 100];
    int e = p - (p / 100) * 100;
    s2 += Wp[p * 100] * csp[e];
  }
  r1[tid] = s1; r2[tid] = s2;
  __syncthreads();
  for (int o = 128; o > 0; o >>= 1) {
    if (tid < o) { r1[tid] += r1[tid + o]; r2[tid] += r2[tid + o]; }
    __syncthreads();
  }
  if (tid == 0) {
    float mean = r2[0] * (1.f / 800000.f);
    float var = r1[0] * (1.f / 800000.f) - mean * mean;
    float g = t ? gEb[f] : gEa[f];
    float bb = t ? bEb[f] : bEa[f];
    float al = rsqrtf(var + EPS_F) * g;
    alpha[t * 100 + f] = al;
    beta[t * 100 + f] = bb - mean * al;
  }
}

// ---------------------------------------------------------------------------
// K8: u, c.  grid (16), block 128
__global__ void k8_u(const float* __restrict__ t01, const float* __restrict__ alpha,
                     const float* __restrict__ beta, const float* __restrict__ Wm,
                     float* __restrict__ u, float* __restrict__ c) {
  int b = blockIdx.x, tid = threadIdx.x;
  __shared__ float w0[100], w1[100], pc[128];
  float p = 0.f;
  if (tid < 100) {
    float t0 = t01[b * 100 + tid], t1 = t01[1600 + b * 100 + tid];
    w0[tid] = t0 * alpha[tid];
    w1[tid] = t1 * alpha[100 + tid];
    p = t0 * beta[tid] + t1 * beta[100 + tid];
  }
  pc[tid] = (tid < 100) ? p : 0.f;
  __syncthreads();
  for (int o = 64; o > 0; o >>= 1) {
    if (tid < o) pc[tid] += pc[tid + o];
    __syncthreads();
  }
  if (tid == 0) c[b] = pc[0];
  if (tid < 100) {
    float sa = 0.f, sb = 0.f;
    const float* wa = Wm + b * 10000 + tid * 100;
    const float* wb = Wm + 160000 + b * 10000 + tid * 100;
    for (int f = 0; f < 100; f++) {
      sa = fmaf(w0[f], wa[f], sa);
      sb = fmaf(w1[f], wb[f], sb);
    }
    u[tid * 16 + b] = sa;
    u[(100 + tid) * 16 + b] = sb;
  }
}

// ---------------------------------------------------------------------------
// K9: score = sigmoid(c + u_a·E_a + u_b·E_b).  grid (196), block 256
__device__ __forceinline__ float f4get(const float4& v, int j) {
  switch (j) { case 0: return v.x; case 1: return v.y; case 2: return v.z; default: return v.w; }
}

__global__ __launch_bounds__(256) void k9_score(const float* __restrict__ E_a,
                                                const float* __restrict__ E_b,
                                                const float* __restrict__ u,
                                                const float* __restrict__ c,
                                                float* __restrict__ out) {
  int n = blockIdx.x * 256 + threadIdx.x;
  if (n >= NE) return;
  const float4* Ea4 = (const float4*)E_a;
  const float4* Eb4 = (const float4*)E_b;
  float acc[16];
#pragma unroll
  for (int b = 0; b < 16; b++) acc[b] = 0.f;
  for (int e4 = 0; e4 < 25; e4++) {
    float4 va = Ea4[n * 25 + e4];
    float4 vb = Eb4[n * 25 + e4];
    const float* ua = u + e4 * 64;
    const float* ub = u + 1600 + e4 * 64;
#pragma unroll
    for (int j = 0; j < 4; j++) {
      float fa = f4get(va, j);
      float fb = f4get(vb, j);
#pragma unroll
      for (int b = 0; b < 16; b++) {
        acc[b] = fmaf(ua[j * 16 + b], fa, acc[b]);
        acc[b] = fmaf(ub[j * 16 + b], fb, acc[b]);
      }
    }
  }
#pragma unroll
  for (int b = 0; b < 16; b++) {
    float x = acc[b] + c[b];
    out[b * NE + n] = 1.f / (1.f + expf(-x));
  }
}

// ---------------------------------------------------------------------------
extern "C" void kernel_launch(void* const* d_in, const int* in_sizes, int n_in,
                              void* d_out, int out_size, void* d_ws, size_t ws_size,
                              hipStream_t stream) {
  const int* h_idx = (const int*)d_in[0];
  const int* r_idx = (const int*)d_in[1];
  const float* E_a = (const float*)d_in[2];
  const float* E_b = (const float*)d_in[3];
  const float* R_re = (const float*)d_in[4];
  const float* R_im = (const float*)d_in[5];
  const float* R2 = (const float*)d_in[6];
  const float* W_re = (const float*)d_in[7];
  const float* W_im = (const float*)d_in[8];
  const float* g0r = (const float*)d_in[9];
  const float* b0r = (const float*)d_in[10];
  const float* g1r = (const float*)d_in[11];
  const float* b1r = (const float*)d_in[12];
  const float* g0i = (const float*)d_in[13];
  const float* b0i = (const float*)d_in[14];
  const float* g1i = (const float*)d_in[15];
  const float* b1i = (const float*)d_in[16];
  const float* gEa = (const float*)d_in[17];
  const float* bEa = (const float*)d_in[18];
  const float* gEb = (const float*)d_in[19];
  const float* bEb = (const float*)d_in[20];
  float* out = (float*)d_out;
  float* ws = (float*)d_ws;

  // fixed regions (350,216 floats)
  float* Wm = ws;                  // [2][16][10000]   320000
  float* G = Wm + 320000;          // [2][10000]        20000
  float* CS = G + 20000;           // [2][100]            200
  float* traw = CS + 200;          // [2][16][100]       3200
  float* t01 = traw + 3200;        // [2][16][100]       3200
  float* alpha = t01 + 3200;       //                     200
  float* beta = alpha + 200;       //                     200
  float* u = beta + 200;           // [2][100][16]       3200
  float* c = u + 3200;             //                      16
  const long fixed = 350216;

  float* un = ws + fixed;          // 16B-aligned (fixed*4 % 16 == 0)
  long avail = (long)(ws_size / 4);
  long unionFloats = avail - fixed - 64;

  // k1 scratch overlaps the union head (lifetime before k2t)
  float* Wm_p = un;                     // 1,280,000 floats
  int splitK1 = (unionFloats >= 1280000);
  if (splitK1) {
    hipLaunchKernelGGL(k1a_wm, dim3(10, 4, 2), dim3(256), 0, stream, W_re, W_im, R2, r_idx, Wm_p);
    hipLaunchKernelGGL(k1b_reduce, dim3(313), dim3(256), 0, stream, Wm_p, Wm);
  } else {
    hipLaunchKernelGGL(k1_wm, dim3(40, 2), dim3(256), 0, stream, W_re, W_im, R2, r_idx, Wm);
  }

  const long etFloats = (2L * 100 * NPAD) / 2;   // bf16 ET as float-count = 5,001,600
  long roomM = (unionFloats - etFloats - 323200) / 20200;
  int NB;
  if (roomM >= 8) {
    // ---- MFMA Gram path ----
    NB = roomM < 128 ? (int)roomM : 128;
    int RPB = ((50016 + NB - 1) / NB + 15) & ~15;
    int seg = (NB + SLICES - 1) / SLICES;
    u16* ET = (u16*)un;
    float* Gp2 = un + etFloats;
    float* CSp2 = Gp2 + 320000;
    float* Gp = CSp2 + 3200;
    float* CSp = Gp + (long)NB * 20000;
    hipLaunchKernelGGL(k2t_transpose, dim3(782, 2), dim3(256), 0, stream, E_a, E_b, ET);
    hipLaunchKernelGGL(k2g_mfma, dim3(NB, 2), dim3(256), 0, stream, ET, Gp, CSp, NB, RPB);
    hipLaunchKernelGGL(k3a_reduce, dim3(40, SLICES, 2), dim3(256), 0, stream,
                       Gp, CSp, Gp2, CSp2, NB, seg);
    hipLaunchKernelGGL(k3b_reduce, dim3(40, 2), dim3(256), 0, stream, Gp2, CSp2, G, CS);
  } else {
    // ---- fallback VALU Gram path ----
    float* Gp2 = un;
    float* CSp2 = Gp2 + 320000;
    float* Gp = CSp2 + 3200;
    long room = (unionFloats - 323200) / 20200;
    NB = room < 360 ? (int)room : 360;
    if (NB < 1) NB = 1;
    int RPB = (NE + NB - 1) / NB;
    int seg = (NB + SLICES - 1) / SLICES;
    float* CSp = Gp + (long)NB * 20000;
    hipLaunchKernelGGL(k2_gram, dim3(NB, 2), dim3(256), 0, stream, E_a, E_b, Gp, CSp, NB, RPB);
    hipLaunchKernelGGL(k3a_reduce, dim3(40, SLICES, 2), dim3(256), 0, stream,
                       Gp, CSp, Gp2, CSp2, NB, seg);
    hipLaunchKernelGGL(k3b_reduce, dim3(40, 2), dim3(256), 0, stream, Gp2, CSp2, G, CS);
  }

  float* P = un;                        // [2][16][10000], after k3b done
  hipLaunchKernelGGL(k4_core1, dim3(16), dim3(256), 0, stream, E_a, E_b, h_idx, Wm,
                     g0r, b0r, g0i, b0i, traw);
  hipLaunchKernelGGL(k5_core2, dim3(1), dim3(256), 0, stream, traw, R_re, R_im, r_idx,
                     g1r, b1r, g1i, b1i, t01);
  hipLaunchKernelGGL(k6_v, dim3(40, 16, 2), dim3(256), 0, stream, Wm, G, P);
  hipLaunchKernelGGL(k7_stats, dim3(100, 2), dim3(256), 0, stream, P, Wm, CS,
                     gEa, bEa, gEb, bEb, alpha, beta);
  hipLaunchKernelGGL(k8_u, dim3(16), dim3(128), 0, stream, t01, alpha, beta, Wm, u, c);
  hipLaunchKernelGGL(k9_score, dim3((NE + 255) / 256), dim3(256), 0, stream,
                     E_a, E_b, u, c, out);
}